// Round 1
// baseline (83.159 us; speedup 1.0000x reference)
//
#include <hip/hip_runtime.h>
#include <hip/hip_bf16.h>

// Problem: B=32, H=28, W=28, C=512 fp32 input. Output [32, 29, 29, 1] fp32.
// out2d[i][j] = boxsum of fsq over clipped window; fsq[h][w] = sum_c x[0,h,w,c]^2.
// Batch dimension is a pure broadcast.

#define HH 28
#define WW 28
#define CC 512
#define BB 32
#define OUTHW ((HH + 1) * (WW + 1))   // 841

// Kernel 1: one block per (h,w). 128 threads * float4 = 512 channels.
__global__ void __launch_bounds__(128)
fsq_kernel(const float* __restrict__ x, float* __restrict__ fsq) {
    const int hw = blockIdx.x;                       // [0, 784)
    const float4* p = reinterpret_cast<const float4*>(x + (size_t)hw * CC);
    const int t = threadIdx.x;
    float4 v = p[t];
    float s = v.x * v.x + v.y * v.y + v.z * v.z + v.w * v.w;
    // wave-64 reduce
    #pragma unroll
    for (int off = 32; off > 0; off >>= 1)
        s += __shfl_down(s, off, 64);
    __shared__ float partial[2];
    if ((t & 63) == 0) partial[t >> 6] = s;
    __syncthreads();
    if (t == 0) fsq[hw] = partial[0] + partial[1];
}

// Kernel 2: single block. Integral image in LDS, box sums, broadcast write.
__global__ void __launch_bounds__(256)
box_kernel(const float* __restrict__ fsq, float* __restrict__ out) {
    __shared__ float I[HH + 1][WW + 2];   // [29][30], +1 col pad
    __shared__ float o2[OUTHW];           // 841
    const int t = threadIdx.x;

    // zero first row / first column of the integral image
    if (t < WW + 1) I[0][t] = 0.f;
    if (t < HH + 1) I[t][0] = 0.f;
    // load fsq into I[1..28][1..28]
    for (int idx = t; idx < HH * WW; idx += 256) {
        int r = idx / WW, c = idx % WW;
        I[r + 1][c + 1] = fsq[idx];
    }
    __syncthreads();

    // horizontal cumsum: one thread per row
    if (t < HH) {
        float s = 0.f;
        #pragma unroll
        for (int c = 1; c <= WW; ++c) { s += I[t + 1][c]; I[t + 1][c] = s; }
    }
    __syncthreads();

    // vertical cumsum: one thread per column
    if (t < WW) {
        float s = 0.f;
        #pragma unroll
        for (int r = 1; r <= HH; ++r) { s += I[r][t + 1]; I[r][t + 1] = s; }
    }
    __syncthreads();

    // box sums with clipped windows
    for (int idx = t; idx < OUTHW; idx += 256) {
        int i = idx / (WW + 1), j = idx % (WW + 1);
        int r0 = min(max(HH / 2 - i, 0), HH);
        int r1 = min(max(HH / 2 + HH - i, 0), HH);
        int c0 = min(max(WW / 2 - j, 0), WW);
        int c1 = min(max(WW / 2 + WW - j, 0), WW);
        o2[idx] = I[r1][c1] - I[r0][c1] - I[r1][c0] + I[r0][c0];
    }
    __syncthreads();

    // broadcast to all 32 batch elements
    for (int idx = t; idx < BB * OUTHW; idx += 256) {
        out[idx] = o2[idx % OUTHW];
    }
}

extern "C" void kernel_launch(void* const* d_in, const int* in_sizes, int n_in,
                              void* d_out, int out_size, void* d_ws, size_t ws_size,
                              hipStream_t stream) {
    const float* x = (const float*)d_in[0];
    float* out = (float*)d_out;
    float* fsq = (float*)d_ws;   // 784 floats

    fsq_kernel<<<HH * WW, 128, 0, stream>>>(x, fsq);
    box_kernel<<<1, 256, 0, stream>>>(fsq, out);
}